// Round 5
// baseline (1692.459 us; speedup 1.0000x reference)
//
#include <hip/hip_runtime.h>
#include <stdint.h>

#define NB 8
#define NPTS 4096
#define NPOINT 1024
#define NSAMPLE 32
#define FCH 64
#define HID 128
#define CAPW 160  // per-wave candidate capacity (expected ~15/segment)

typedef unsigned long long ull;

// d2 computed with EXACT numpy rounding/order: ((dx*dx + dy*dy) + dz*dz),
// no FMA contraction (FPS argmax + radius selection must match ref bitwise).
__device__ __forceinline__ float d2_exact(float ax, float ay, float az,
                                          float bx, float by, float bz) {
  float dx = ax - bx, dy = ay - by, dz = az - bz;
  return __fadd_rn(__fadd_rn(__fmul_rn(dx, dx), __fmul_rn(dy, dy)),
                   __fmul_rn(dz, dz));
}

// DPP f32 max step (identity 0 valid: dists >= 0). VALU pipe.
#define DPPMAX(v, ctrl)                                                     \
  v = fmaxf(v, __int_as_float(__builtin_amdgcn_update_dpp(                  \
                 0, __float_as_int(v), ctrl, 0xf, 0xf, true)))

// ---------------- shared-memory union (producer ~50KB / consumer ~42KB) ----
// <=53.3KB -> 3 blocks/CU (the R4 fix: 66.4KB forced 1 block/CU at grid=256,
// occupancy 12%, consumers throughput-starved at 8 q/us).
struct ProdS {
  float xs[NPTS], ys[NPTS], zs[NPTS];  // 48 KB SoA (was float4 64KB)
  float chunk[64 * 3];                 // 64-centroid publish buffer
  float4 wkd4[2];                      // per-wave max dist (parity dbuf)
  int4 wki4[2];                        // per-wave argmax idx
};
struct ConsS {
  float fin[32][68];  // dxyz 0..2, feats 3..66, pad 67
  float fm[HID];
  int sidx[NSAMPLE];
  int scnt[4];
  int tkS;
  union {  // knn candidates overlaid on GEMM buffers (dead during knn)
    float bufA[32][HID];  // h1 then h2
    ull candseg[4][CAPW];
  };
  union {
    float fp[32][HID];  // f_prime
    ull cand2[4 * CAPW];
  };
};
union SMemU {
  ProdS p;
  ConsS c;
};

// ---------------------------------------------------------------- FPS
// R3-proven chain: 256 thr, 16 pts/thread in regs, DPP wave argmax, parity
// LDS exchange. Publishes centroids in 64-chunks (flush stores by waves 0-2
// + threadfence, barrier, release-store of progress[b]). Runs at prio 3 so
// co-resident consumer waves don't stretch the latency chain.
__device__ void run_fps(const float* __restrict__ xyz,
                        float* __restrict__ newxyz, int* progress, int b,
                        ProdS& S) {
  __builtin_amdgcn_s_setprio(3);
  const int t = threadIdx.x;
  const int wid = t >> 6;
  const float* src = xyz + (size_t)b * NPTS * 3;
  float* dstb = newxyz + (size_t)b * NPOINT * 3;
  for (int j = t; j < NPTS; j += 256) {
    S.xs[j] = src[3 * j + 0];
    S.ys[j] = src[3 * j + 1];
    S.zs[j] = src[3 * j + 2];
  }
  __syncthreads();
  const int base = t * 16;
  float px[16], py[16], pz[16], dist[16];
  const float c0x = S.xs[0], c0y = S.ys[0], c0z = S.zs[0];
  float bv = -INFINITY;
  int br = 0;
#pragma unroll
  for (int r = 0; r < 16; ++r) {
    px[r] = S.xs[base + r];
    py[r] = S.ys[base + r];
    pz[r] = S.zs[base + r];
    dist[r] = d2_exact(px[r], py[r], pz[r], c0x, c0y, c0z);
    bool c = dist[r] > bv;  // strict > keeps lowest r (idx) on ties
    bv = c ? dist[r] : bv;
    br = c ? r : br;
  }
  if (t == 0) {
    S.chunk[0] = c0x; S.chunk[1] = c0y; S.chunk[2] = c0z;
  }
  for (int it = 1; it < NPOINT; ++it) {
    float wm = bv;
    DPPMAX(wm, 0x111); DPPMAX(wm, 0x112); DPPMAX(wm, 0x114); DPPMAX(wm, 0x118);
    DPPMAX(wm, 0x142); DPPMAX(wm, 0x143);
    float gmaxw =
        __int_as_float(__builtin_amdgcn_readlane(__float_as_int(wm), 63));
    ull m = __ballot(bv == gmaxw);
    int lead = __ffsll((long long)m) - 1;  // lowest lane == lowest index
    int widx = __builtin_amdgcn_readlane(base + br, lead);
    const int par = it & 1;
    if ((t & 63) == 0) {
      ((float*)&S.wkd4[par])[wid] = gmaxw;
      ((int*)&S.wki4[par])[wid] = widx;
    }
    __syncthreads();  // parity double-buffer -> single barrier/iter
    if ((it & 63) == 0) {
      if (t < 192) {
        dstb[(it - 64) * 3 + t] = S.chunk[t];
        __threadfence();
      }
      __syncthreads();
      if (t == 0)
        __hip_atomic_store(&progress[b], it, __ATOMIC_RELEASE,
                           __HIP_MEMORY_SCOPE_AGENT);
    }
    float4 dd = S.wkd4[par];
    int4 ii = S.wki4[par];
    float d = dd.x; int fi = ii.x;
    bool c1 = (dd.y > d) || (dd.y == d && ii.y < fi);
    d = c1 ? dd.y : d; fi = c1 ? ii.y : fi;
    bool c2 = (dd.z > d) || (dd.z == d && ii.z < fi);
    d = c2 ? dd.z : d; fi = c2 ? ii.z : fi;
    bool c3 = (dd.w > d) || (dd.w == d && ii.w < fi);
    fi = c3 ? ii.w : fi;
    const float cpx = S.xs[fi], cpy = S.ys[fi], cpz = S.zs[fi];
    if (t == 0) {
      int slot = (it & 63) * 3;
      S.chunk[slot + 0] = cpx;
      S.chunk[slot + 1] = cpy;
      S.chunk[slot + 2] = cpz;
    }
    bv = -INFINITY;
    br = 0;
#pragma unroll
    for (int r = 0; r < 16; ++r) {
      float dnew = d2_exact(px[r], py[r], pz[r], cpx, cpy, cpz);
      float nd = fminf(dist[r], dnew);
      dist[r] = nd;
      bool c = nd > bv;
      bv = c ? nd : bv;
      br = c ? r : br;
    }
  }
  __syncthreads();  // chunk holds centroids [960,1024)
  if (t < 192) {
    dstb[(NPOINT - 64) * 3 + t] = S.chunk[t];
    __threadfence();
  }
  __syncthreads();
  if (t == 0)
    __hip_atomic_store(&progress[b], NPOINT, __ATOMIC_RELEASE,
                       __HIP_MEMORY_SCOPE_AGENT);
  __builtin_amdgcn_s_setprio(0);
}

// ---------------------------------------------------------------- MLP gemms
// W streamed from global/L2 (R1/R3-proven; LDS staging spilled in R2).
template <int K>
__device__ __forceinline__ void gemm_tile(const float* __restrict__ a0,
                                          const float* __restrict__ a1,
                                          const float* __restrict__ a2,
                                          const float* __restrict__ a3,
                                          const float* __restrict__ W,
                                          float acc[4][4]) {
  int k = 0;
  for (; k + 4 <= K; k += 4) {
    float4 A0 = *(const float4*)(a0 + k);
    float4 A1 = *(const float4*)(a1 + k);
    float4 A2 = *(const float4*)(a2 + k);
    float4 A3 = *(const float4*)(a3 + k);
#pragma unroll
    for (int kk = 0; kk < 4; ++kk) {
      float4 w = *(const float4*)(W + (size_t)(k + kk) * HID);
      float e0 = (&A0.x)[kk], e1 = (&A1.x)[kk], e2 = (&A2.x)[kk], e3 = (&A3.x)[kk];
      acc[0][0] += e0 * w.x; acc[0][1] += e0 * w.y; acc[0][2] += e0 * w.z; acc[0][3] += e0 * w.w;
      acc[1][0] += e1 * w.x; acc[1][1] += e1 * w.y; acc[1][2] += e1 * w.z; acc[1][3] += e1 * w.w;
      acc[2][0] += e2 * w.x; acc[2][1] += e2 * w.y; acc[2][2] += e2 * w.z; acc[2][3] += e2 * w.w;
      acc[3][0] += e3 * w.x; acc[3][1] += e3 * w.y; acc[3][2] += e3 * w.z; acc[3][3] += e3 * w.w;
    }
  }
  for (; k < K; ++k) {
    float4 w = *(const float4*)(W + (size_t)k * HID);
    float e0 = a0[k], e1 = a1[k], e2 = a2[k], e3 = a3[k];
    acc[0][0] += e0 * w.x; acc[0][1] += e0 * w.y; acc[0][2] += e0 * w.z; acc[0][3] += e0 * w.w;
    acc[1][0] += e1 * w.x; acc[1][1] += e1 * w.y; acc[1][2] += e1 * w.z; acc[1][3] += e1 * w.w;
    acc[2][0] += e2 * w.x; acc[2][1] += e2 * w.y; acc[2][2] += e2 * w.z; acc[2][3] += e2 * w.w;
    acc[3][0] += e3 * w.x; acc[3][1] += e3 * w.y; acc[3][2] += e3 * w.z; acc[3][3] += e3 * w.w;
  }
}

__device__ __forceinline__ void gemm_tile_corr(const float* __restrict__ a0,
                                               const float* __restrict__ a1,
                                               const float* __restrict__ a2,
                                               const float* __restrict__ a3,
                                               const float* __restrict__ W,
                                               const float* __restrict__ fm,
                                               float acc[4][4], float corr[4]) {
  for (int k = 0; k < HID; k += 4) {
    float4 A0 = *(const float4*)(a0 + k);
    float4 A1 = *(const float4*)(a1 + k);
    float4 A2 = *(const float4*)(a2 + k);
    float4 A3 = *(const float4*)(a3 + k);
    float4 FM = *(const float4*)(fm + k);
#pragma unroll
    for (int kk = 0; kk < 4; ++kk) {
      float4 w = *(const float4*)(W + (size_t)(k + kk) * HID);
      float e0 = (&A0.x)[kk], e1 = (&A1.x)[kk], e2 = (&A2.x)[kk], e3 = (&A3.x)[kk];
      float cf = (&FM.x)[kk];
      acc[0][0] += e0 * w.x; acc[0][1] += e0 * w.y; acc[0][2] += e0 * w.z; acc[0][3] += e0 * w.w;
      acc[1][0] += e1 * w.x; acc[1][1] += e1 * w.y; acc[1][2] += e1 * w.z; acc[1][3] += e1 * w.w;
      acc[2][0] += e2 * w.x; acc[2][1] += e2 * w.y; acc[2][2] += e2 * w.z; acc[2][3] += e2 * w.w;
      acc[3][0] += e3 * w.x; acc[3][1] += e3 * w.y; acc[3][2] += e3 * w.z; acc[3][3] += e3 * w.w;
      corr[0] += cf * w.x; corr[1] += cf * w.y; corr[2] += cf * w.z; corr[3] += cf * w.w;
    }
  }
}

// ---------------------------------------------------------------- consumer
__device__ void run_consumer(const float* __restrict__ xyz,
                             const float* __restrict__ feats,
                             const float* __restrict__ W1f,
                             const float* __restrict__ b1f,
                             const float* __restrict__ W2f,
                             const float* __restrict__ b2f,
                             const float* __restrict__ W1w,
                             const float* __restrict__ b1w,
                             const float* __restrict__ W2w,
                             const float* __restrict__ b2w,
                             const float* __restrict__ newxyz,
                             float* __restrict__ fout, int* progress,
                             int* ticket, ConsS& S) {
  const int t = threadIdx.x;
  const int wv = t >> 6;
  const int lane = t & 63;
  const float r2 = 0.0225f;  // np float32(RADIUS**2)

  while (true) {
    if (t == 0) S.tkS = atomicAdd(ticket, 1);
    __syncthreads();
    const int tk = S.tkS;
    if (tk >= NB * NPOINT) return;
    const int it = tk >> 3;
    const int b = tk & 7;
    const int g = b * NPOINT + it;

    // wait until centroid `it` of batch b is published
    if (t == 0) {
      while (__hip_atomic_load(&progress[b], __ATOMIC_RELAXED,
                               __HIP_MEMORY_SCOPE_AGENT) <= it)
        __builtin_amdgcn_s_sleep(32);
    }
    __syncthreads();
    {  // every thread acquires (orders its own subsequent loads)
      int pv = __hip_atomic_load(&progress[b], __ATOMIC_ACQUIRE,
                                 __HIP_MEMORY_SCOPE_AGENT);
      while (pv <= it) {
        __builtin_amdgcn_s_sleep(8);
        pv = __hip_atomic_load(&progress[b], __ATOMIC_ACQUIRE,
                               __HIP_MEMORY_SCOPE_AGENT);
      }
    }
    const float cx = newxyz[g * 3 + 0];
    const float cy = newxyz[g * 3 + 1];
    const float cz = newxyz[g * 3 + 2];

    // ---- knn: 4-wave scan, per-wave compaction, rank-select 32 smallest
    const float* src = xyz + (size_t)b * NPTS * 3;
    int cnt = 0;
    const int jb = wv * 1024;
    for (int j0 = jb; j0 < jb + 1024; j0 += 64) {
      const int p = j0 + lane;
      const float* pp = src + p * 3;
      float d2 = d2_exact(pp[0], pp[1], pp[2], cx, cy, cz);
      bool inr = (d2 <= r2);
      ull mask = __ballot(inr);
      if (inr) {
        int pos = cnt + __popcll(mask & ((1ull << lane) - 1ull));
        if (pos < CAPW)
          S.candseg[wv][pos] = ((ull)__float_as_uint(d2) << 32) | (unsigned)p;
      }
      cnt += __popcll(mask);
    }
    if (lane == 0) S.scnt[wv] = cnt < CAPW ? cnt : CAPW;
    __syncthreads();
    const int n0 = S.scnt[0], n1 = S.scnt[1], n2 = S.scnt[2], n3 = S.scnt[3];
    const int C = n0 + n1 + n2 + n3;
    {
      int off = (wv > 0 ? n0 : 0) + (wv > 1 ? n1 : 0) + (wv > 2 ? n2 : 0);
      int myn = S.scnt[wv];
      for (int i = lane; i < myn; i += 64) S.cand2[off + i] = S.candseg[wv][i];
    }
    __syncthreads();
    for (int tt = t; tt < C; tt += 256) {
      ull key = S.cand2[tt];
      int rank = 0;
      for (int u = 0; u < C; ++u) rank += (S.cand2[u] < key) ? 1 : 0;
      if (rank < NSAMPLE) S.sidx[rank] = (int)(key & 0xffffffffu);
    }
    if (C < NSAMPLE && wv == 0) {  // boundary fill: lowest-index outside pts
      const float* pp = src + lane * 3;
      float d2 = d2_exact(pp[0], pp[1], pp[2], cx, cy, cz);
      bool outr = !(d2 <= r2);
      ull mask = __ballot(outr);
      if (outr) {
        int pos = __popcll(mask & ((1ull << lane) - 1ull));
        if (pos < NSAMPLE - C) S.sidx[C + pos] = lane;
      }
    }
    __syncthreads();

    // ---- mlp (R3-proven structure)
    if (t < 32) {
      const float* pp = src + (size_t)S.sidx[t] * 3;
      S.fin[t][0] = pp[0] - cx;
      S.fin[t][1] = pp[1] - cy;
      S.fin[t][2] = pp[2] - cz;
      S.fin[t][67] = 0.f;
    }
    for (int e = t; e < 32 * FCH; e += 256) {
      int s = e >> 6;
      int c = e & 63;
      S.fin[s][3 + c] = feats[((size_t)b * NPTS + S.sidx[s]) * FCH + c];
    }
    __syncthreads();

    const int s0 = (t >> 5) * 4;
    const int c0 = (t & 31) * 4;
    float acc[4][4];

    // G1
    {
      float4 bv4 = *(const float4*)(b1f + c0);
#pragma unroll
      for (int i = 0; i < 4; ++i) { acc[i][0] = bv4.x; acc[i][1] = bv4.y; acc[i][2] = bv4.z; acc[i][3] = bv4.w; }
    }
    gemm_tile<67>(S.fin[s0], S.fin[s0 + 1], S.fin[s0 + 2], S.fin[s0 + 3],
                  W1f + c0, acc);
#pragma unroll
    for (int i = 0; i < 4; ++i)
#pragma unroll
      for (int j = 0; j < 4; ++j) S.bufA[s0 + i][c0 + j] = fmaxf(acc[i][j], 0.f);
    __syncthreads();

    // G2
    {
      float4 bv4 = *(const float4*)(b2f + c0);
#pragma unroll
      for (int i = 0; i < 4; ++i) { acc[i][0] = bv4.x; acc[i][1] = bv4.y; acc[i][2] = bv4.z; acc[i][3] = bv4.w; }
    }
    gemm_tile<128>(S.bufA[s0], S.bufA[s0 + 1], S.bufA[s0 + 2], S.bufA[s0 + 3],
                   W2f + c0, acc);
#pragma unroll
    for (int i = 0; i < 4; ++i)
#pragma unroll
      for (int j = 0; j < 4; ++j) S.fp[s0 + i][c0 + j] = fmaxf(acc[i][j], 0.f);
    __syncthreads();

    if (t < HID) {
      float s = 0.f;
#pragma unroll 8
      for (int i = 0; i < 32; ++i) s += S.fp[i][t];
      S.fm[t] = s * (1.0f / 32.0f);
    }
    __syncthreads();

    // G3: relu( fp@W1w[3:] + (b1w + dxyz@W1w[0:3]) - fm@W1w[3:] )
    float corr[4] = {0.f, 0.f, 0.f, 0.f};
    {
      float4 bv4 = *(const float4*)(b1w + c0);
      float4 w0 = *(const float4*)(W1w + 0 * HID + c0);
      float4 w1 = *(const float4*)(W1w + 1 * HID + c0);
      float4 w2 = *(const float4*)(W1w + 2 * HID + c0);
#pragma unroll
      for (int i = 0; i < 4; ++i) {
        float dx = S.fin[s0 + i][0], dy = S.fin[s0 + i][1], dz = S.fin[s0 + i][2];
        acc[i][0] = bv4.x + dx * w0.x + dy * w1.x + dz * w2.x;
        acc[i][1] = bv4.y + dx * w0.y + dy * w1.y + dz * w2.y;
        acc[i][2] = bv4.z + dx * w0.z + dy * w1.z + dz * w2.z;
        acc[i][3] = bv4.w + dx * w0.w + dy * w1.w + dz * w2.w;
      }
    }
    gemm_tile_corr(S.fp[s0], S.fp[s0 + 1], S.fp[s0 + 2], S.fp[s0 + 3],
                   W1w + 3 * HID + c0, S.fm, acc, corr);
    __syncthreads();
#pragma unroll
    for (int i = 0; i < 4; ++i)
#pragma unroll
      for (int j = 0; j < 4; ++j)
        S.bufA[s0 + i][c0 + j] = fmaxf(acc[i][j] - corr[j], 0.f);
    __syncthreads();

    // G4
    {
      float4 bv4 = *(const float4*)(b2w + c0);
#pragma unroll
      for (int i = 0; i < 4; ++i) { acc[i][0] = bv4.x; acc[i][1] = bv4.y; acc[i][2] = bv4.z; acc[i][3] = bv4.w; }
    }
    gemm_tile<128>(S.bufA[s0], S.bufA[s0 + 1], S.bufA[s0 + 2], S.bufA[s0 + 3],
                   W2w + c0, acc);
    {
      float part[4] = {0.f, 0.f, 0.f, 0.f};
#pragma unroll
      for (int i = 0; i < 4; ++i)
#pragma unroll
        for (int j = 0; j < 4; ++j) {
          float al = 1.0f / (1.0f + __expf(-acc[i][j]));
          part[j] += al * S.fp[s0 + i][c0 + j];
        }
      __syncthreads();  // fin dead -> reuse as 8xHID reduction buffer
      float* redp = &S.fin[0][0];
      redp[(t >> 5) * HID + c0 + 0] = part[0];
      redp[(t >> 5) * HID + c0 + 1] = part[1];
      redp[(t >> 5) * HID + c0 + 2] = part[2];
      redp[(t >> 5) * HID + c0 + 3] = part[3];
    }
    __syncthreads();
    if (t < HID) {
      float* redp = &S.fin[0][0];
      float s = 0.f;
#pragma unroll
      for (int w = 0; w < 8; ++w) s += redp[w * HID + t];
      fout[(size_t)g * HID + t] = s;
    }
    __syncthreads();  // LDS fully consumed before next ticket
  }
}

// ---------------------------------------------------------------- fused
__global__ __launch_bounds__(256, 3) void sa_fused_kernel(
    const float* __restrict__ xyz, const float* __restrict__ feats,
    const float* __restrict__ W1f, const float* __restrict__ b1f,
    const float* __restrict__ W2f, const float* __restrict__ b2f,
    const float* __restrict__ W1w, const float* __restrict__ b1w,
    const float* __restrict__ W2w, const float* __restrict__ b2w,
    float* __restrict__ newxyz, float* __restrict__ fout, int* ctrl) {
  __shared__ SMemU sm;
  int* progress = ctrl;    // [0..7]
  int* ticket = ctrl + 8;  // [8]
  if (blockIdx.x < NB) {
    run_fps(xyz, newxyz, progress, blockIdx.x, sm.p);
    __syncthreads();
  }
  run_consumer(xyz, feats, W1f, b1f, W2f, b2f, W1w, b1w, W2w, b2w, newxyz,
               fout, progress, ticket, sm.c);
}

extern "C" void kernel_launch(void* const* d_in, const int* in_sizes, int n_in,
                              void* d_out, int out_size, void* d_ws, size_t ws_size,
                              hipStream_t stream) {
  const float* xyz = (const float*)d_in[0];
  const float* feats = (const float*)d_in[1];
  const float* W1f = (const float*)d_in[2];
  const float* b1f = (const float*)d_in[3];
  const float* W2f = (const float*)d_in[4];
  const float* b2f = (const float*)d_in[5];
  const float* W1w = (const float*)d_in[6];
  const float* b1w = (const float*)d_in[7];
  const float* W2w = (const float*)d_in[8];
  const float* b2w = (const float*)d_in[9];

  float* newxyz = (float*)d_out;                          // (8,1024,3)
  float* fout = (float*)d_out + (size_t)NB * NPOINT * 3;  // (8,1024,128)
  int* ctrl = (int*)d_ws;  // progress[8] + ticket[1]

  hipMemsetAsync(ctrl, 0, 64, stream);
  // 768 blocks = 3/CU (LDS ~50KB x3 <= 160KB). Producers are blocks 0-7,
  // dispatched first -> always resident; consumers never wait on consumers,
  // so late-dispatched blocks cannot deadlock.
  sa_fused_kernel<<<768, 256, 0, stream>>>(xyz, feats, W1f, b1f, W2f, b2f,
                                           W1w, b1w, W2w, b2w, newxyz, fout,
                                           ctrl);
}